// Round 1
// baseline (402.870 us; speedup 1.0000x reference)
//
#include <hip/hip_runtime.h>
#include <math.h>

#define BB 64
#define PP 1024
#define DD 768

// ---------------------------------------------------------------------------
// qw[d] = sum_e q[e] * W[e*D + d]   (collapses the k=zW^T GEMM into a vector)
// ---------------------------------------------------------------------------
__global__ __launch_bounds__(256) void qw_kernel(const float* __restrict__ q,
                                                 const float* __restrict__ W,
                                                 float* __restrict__ qw) {
    __shared__ float qs[DD];
    int tid = threadIdx.x;
    for (int i = tid; i < DD; i += 256) qs[i] = q[i];
    __syncthreads();
    int d = blockIdx.x * 256 + tid;   // grid.x = 3 -> d in [0,768)
    float acc = 0.f;
#pragma unroll 4
    for (int e = 0; e < DD; ++e) acc += qs[e] * W[(size_t)e * DD + d];
    qw[d] = acc;
}

// ---------------------------------------------------------------------------
// scores[b,p] = scale * dot(z[b,p,:], qw)   — one wave per row p
// ---------------------------------------------------------------------------
__global__ __launch_bounds__(256) void scores_kernel(const float* __restrict__ z,
                                                     const float* __restrict__ qw,
                                                     float* __restrict__ scores) {
    __shared__ float4 qws[DD / 4];          // 3 KB
    int tid = threadIdx.x;
    const float4* qw4 = (const float4*)qw;
    if (tid < DD / 4) qws[tid] = qw4[tid];
    __syncthreads();

    int b     = blockIdx.x >> 8;            // / 256
    int pbase = (blockIdx.x & 255) * 4;
    int wave  = tid >> 6;
    int lane  = tid & 63;
    int p     = pbase + wave;

    const float4* z4 = (const float4*)(z + ((size_t)b * PP + p) * DD);
    float acc = 0.f;
#pragma unroll
    for (int j = 0; j < 3; ++j) {
        float4 zv = z4[lane + 64 * j];
        float4 qv = qws[lane + 64 * j];
        acc += zv.x * qv.x + zv.y * qv.y + zv.z * qv.z + zv.w * qv.w;
    }
#pragma unroll
    for (int off = 32; off >= 1; off >>= 1)
        acc += __shfl_xor(acc, off, 64);

    if (lane == 0)
        scores[b * PP + p] = acc * 0.03608439182435161f;   // 1/sqrt(768)
}

// ---------------------------------------------------------------------------
// softmax over P per batch: attn[b,p] = exp(s-m)/sum
// ---------------------------------------------------------------------------
__global__ __launch_bounds__(1024) void softmax_kernel(const float* __restrict__ scores,
                                                       float* __restrict__ attn) {
    int b = blockIdx.x;
    int tid = threadIdx.x;
    int wave = tid >> 6, lane = tid & 63;

    float s = scores[b * PP + tid];

    __shared__ float redm[16];
    float m = s;
#pragma unroll
    for (int off = 32; off >= 1; off >>= 1) m = fmaxf(m, __shfl_xor(m, off, 64));
    if (lane == 0) redm[wave] = m;
    __syncthreads();
    if (wave == 0) {
        float v = (lane < 16) ? redm[lane] : -INFINITY;
#pragma unroll
        for (int off = 8; off >= 1; off >>= 1) v = fmaxf(v, __shfl_xor(v, off, 64));
        if (lane == 0) redm[0] = v;
    }
    __syncthreads();
    m = redm[0];

    float e = __expf(s - m);

    __shared__ float reds[16];
    float t = e;
#pragma unroll
    for (int off = 32; off >= 1; off >>= 1) t += __shfl_xor(t, off, 64);
    if (lane == 0) reds[wave] = t;
    __syncthreads();
    if (wave == 0) {
        float v = (lane < 16) ? reds[lane] : 0.f;
#pragma unroll
        for (int off = 8; off >= 1; off >>= 1) v += __shfl_xor(v, off, 64);
        if (lane == 0) reds[0] = v;
    }
    __syncthreads();

    attn[b * PP + tid] = e / reds[0];
}

// ---------------------------------------------------------------------------
// pooled[b,d] = sum_p attn[b,p] * z[b,p,d]
// ---------------------------------------------------------------------------
__global__ __launch_bounds__(256) void zero_out_kernel(float* __restrict__ out) {
    int i = blockIdx.x * 256 + threadIdx.x;
    if (i < BB * DD) out[i] = 0.f;
}

__global__ __launch_bounds__(256) void pool_kernel(const float* __restrict__ z,
                                                   const float* __restrict__ attn,
                                                   float* __restrict__ out) {
    int b  = blockIdx.x;        // 64
    int dc = blockIdx.y;        // 3
    int ps = blockIdx.z;        // 8 p-splits of 128
    int tid = threadIdx.x;
    int d  = dc * 256 + tid;
    int p0 = ps * 128;

    __shared__ float aw[128];
    if (tid < 128) aw[tid] = attn[b * PP + p0 + tid];
    __syncthreads();

    const float* zb = z + ((size_t)b * PP + p0) * DD + d;
    float acc = 0.f;
#pragma unroll 4
    for (int i = 0; i < 128; ++i) acc += aw[i] * zb[(size_t)i * DD];

    atomicAdd(&out[b * DD + d], acc);   // 8 contenders per element — negligible
}

// ---------------------------------------------------------------------------
extern "C" void kernel_launch(void* const* d_in, const int* in_sizes, int n_in,
                              void* d_out, int out_size, void* d_ws, size_t ws_size,
                              hipStream_t stream) {
    const float* z = (const float*)d_in[0];   // [B,P,D]
    const float* q = (const float*)d_in[1];   // [1,1,D]
    const float* W = (const float*)d_in[2];   // [D,D]
    float* out = (float*)d_out;               // [B,D]

    char* ws = (char*)d_ws;
    float* qw     = (float*)ws;                                   // 768 f
    float* scores = (float*)(ws + 4096);                          // B*P f
    float* attn   = (float*)(ws + 4096 + (size_t)BB * PP * 4);    // B*P f

    qw_kernel<<<3, 256, 0, stream>>>(q, W, qw);
    scores_kernel<<<BB * PP / 4, 256, 0, stream>>>(z, qw, scores);
    softmax_kernel<<<BB, 1024, 0, stream>>>(scores, attn);
    zero_out_kernel<<<(BB * DD + 255) / 256, 256, 0, stream>>>(out);
    dim3 pg(BB, 3, 8);
    pool_kernel<<<pg, 256, 0, stream>>>(z, attn, out);
}

// Round 2
// 305.652 us; speedup vs baseline: 1.3181x; 1.3181x over previous
//
#include <hip/hip_runtime.h>
#include <math.h>

#define BB 64
#define PP 1024
#define DD 768

// ---------------------------------------------------------------------------
// zero qw[768] and out[B*D] (pool + qw use atomicAdd)
// ---------------------------------------------------------------------------
__global__ __launch_bounds__(256) void zero_kernel(float* __restrict__ qw,
                                                   float* __restrict__ out) {
    int i = blockIdx.x * 256 + threadIdx.x;
    if (i < DD) qw[i] = 0.f;
    if (i < BB * DD) out[i] = 0.f;
}

// ---------------------------------------------------------------------------
// qw[d] = sum_e q[e] * W[e*D + d]   (collapses the k=zW^T GEMM into a vector)
// grid (3, 32): d-chunk of 256, e-chunk of 24. atomicAdd combine.
// ---------------------------------------------------------------------------
__global__ __launch_bounds__(256) void qw_kernel(const float* __restrict__ q,
                                                 const float* __restrict__ W,
                                                 float* __restrict__ qw) {
    int d  = blockIdx.x * 256 + threadIdx.x;
    int e0 = blockIdx.y * 24;
    float acc = 0.f;
#pragma unroll
    for (int i = 0; i < 24; ++i) {
        int e = e0 + i;
        acc += q[e] * W[(size_t)e * DD + d];   // q[e] is wave-uniform -> s_load
    }
    atomicAdd(&qw[d], acc);                    // 32 contenders per element
}

// ---------------------------------------------------------------------------
// scores[b,p] = scale * dot(z[b,p,:], qw)   — one wave per row p
// ---------------------------------------------------------------------------
__global__ __launch_bounds__(256) void scores_kernel(const float* __restrict__ z,
                                                     const float* __restrict__ qw,
                                                     float* __restrict__ scores) {
    __shared__ float4 qws[DD / 4];          // 3 KB
    int tid = threadIdx.x;
    const float4* qw4 = (const float4*)qw;
    if (tid < DD / 4) qws[tid] = qw4[tid];
    __syncthreads();

    int b     = blockIdx.x >> 8;            // / 256
    int pbase = (blockIdx.x & 255) * 4;
    int wave  = tid >> 6;
    int lane  = tid & 63;
    int p     = pbase + wave;

    const float4* z4 = (const float4*)(z + ((size_t)b * PP + p) * DD);
    float acc = 0.f;
#pragma unroll
    for (int j = 0; j < 3; ++j) {
        float4 zv = z4[lane + 64 * j];
        float4 qv = qws[lane + 64 * j];
        acc += zv.x * qv.x + zv.y * qv.y + zv.z * qv.z + zv.w * qv.w;
    }
#pragma unroll
    for (int off = 32; off >= 1; off >>= 1)
        acc += __shfl_xor(acc, off, 64);

    if (lane == 0)
        scores[b * PP + p] = acc * 0.03608439182435161f;   // 1/sqrt(768)
}

// ---------------------------------------------------------------------------
// softmax over P per batch: attn[b,p] = exp(s-m)/sum
// ---------------------------------------------------------------------------
__global__ __launch_bounds__(1024) void softmax_kernel(const float* __restrict__ scores,
                                                       float* __restrict__ attn) {
    int b = blockIdx.x;
    int tid = threadIdx.x;
    int wave = tid >> 6, lane = tid & 63;

    float s = scores[b * PP + tid];

    __shared__ float redm[16];
    float m = s;
#pragma unroll
    for (int off = 32; off >= 1; off >>= 1) m = fmaxf(m, __shfl_xor(m, off, 64));
    if (lane == 0) redm[wave] = m;
    __syncthreads();
    if (wave == 0) {
        float v = (lane < 16) ? redm[lane] : -INFINITY;
#pragma unroll
        for (int off = 8; off >= 1; off >>= 1) v = fmaxf(v, __shfl_xor(v, off, 64));
        if (lane == 0) redm[0] = v;
    }
    __syncthreads();
    m = redm[0];

    float e = __expf(s - m);

    __shared__ float reds[16];
    float t = e;
#pragma unroll
    for (int off = 32; off >= 1; off >>= 1) t += __shfl_xor(t, off, 64);
    if (lane == 0) reds[wave] = t;
    __syncthreads();
    if (wave == 0) {
        float v = (lane < 16) ? reds[lane] : 0.f;
#pragma unroll
        for (int off = 8; off >= 1; off >>= 1) v += __shfl_xor(v, off, 64);
        if (lane == 0) reds[0] = v;
    }
    __syncthreads();

    attn[b * PP + tid] = e / reds[0];
}

// ---------------------------------------------------------------------------
// pooled[b,d] = sum_p attn[b,p] * z[b,p,d]
// ---------------------------------------------------------------------------
__global__ __launch_bounds__(256) void pool_kernel(const float* __restrict__ z,
                                                   const float* __restrict__ attn,
                                                   float* __restrict__ out) {
    int b  = blockIdx.x;        // 64
    int dc = blockIdx.y;        // 3
    int ps = blockIdx.z;        // 8 p-splits of 128
    int tid = threadIdx.x;
    int d  = dc * 256 + tid;
    int p0 = ps * 128;

    __shared__ float aw[128];
    if (tid < 128) aw[tid] = attn[b * PP + p0 + tid];
    __syncthreads();

    const float* zb = z + ((size_t)b * PP + p0) * DD + d;
    float acc = 0.f;
#pragma unroll 4
    for (int i = 0; i < 128; ++i) acc += aw[i] * zb[(size_t)i * DD];

    atomicAdd(&out[b * DD + d], acc);   // 8 contenders per element — negligible
}

// ---------------------------------------------------------------------------
extern "C" void kernel_launch(void* const* d_in, const int* in_sizes, int n_in,
                              void* d_out, int out_size, void* d_ws, size_t ws_size,
                              hipStream_t stream) {
    const float* z = (const float*)d_in[0];   // [B,P,D]
    const float* q = (const float*)d_in[1];   // [1,1,D]
    const float* W = (const float*)d_in[2];   // [D,D]
    float* out = (float*)d_out;               // [B,D]

    char* ws = (char*)d_ws;
    float* qw     = (float*)ws;                                   // 768 f
    float* scores = (float*)(ws + 4096);                          // B*P f
    float* attn   = (float*)(ws + 4096 + (size_t)BB * PP * 4);    // B*P f

    zero_kernel<<<(BB * DD + 255) / 256, 256, 0, stream>>>(qw, out);
    dim3 qg(3, 32);
    qw_kernel<<<qg, 256, 0, stream>>>(q, W, qw);
    scores_kernel<<<BB * PP / 4, 256, 0, stream>>>(z, qw, scores);
    softmax_kernel<<<BB, 1024, 0, stream>>>(scores, attn);
    dim3 pg(BB, 3, 8);
    pool_kernel<<<pg, 256, 0, stream>>>(z, attn, out);
}

// Round 3
// 294.698 us; speedup vs baseline: 1.3671x; 1.0372x over previous
//
#include <hip/hip_runtime.h>
#include <math.h>

#define BB 64
#define PP 1024
#define DD 768
#define PS 16            // p-splits per batch (64 rows each, 16 rows per wave)
#define NPART 64         // partials per batch = PS * 4 waves

// ---------------------------------------------------------------------------
// qw[d] = sum_e q[e] * W[e*D + d]  — grid (3, 32), atomicAdd combine
// ---------------------------------------------------------------------------
__global__ __launch_bounds__(256) void qw_kernel(const float* __restrict__ q,
                                                 const float* __restrict__ W,
                                                 float* __restrict__ qw) {
    int d  = blockIdx.x * 256 + threadIdx.x;
    int e0 = blockIdx.y * 24;
    float acc = 0.f;
#pragma unroll
    for (int i = 0; i < 24; ++i) {
        int e = e0 + i;
        acc += q[e] * W[(size_t)e * DD + d];   // q[e] wave-uniform -> scalar load
    }
    atomicAdd(&qw[d], acc);
}

// ---------------------------------------------------------------------------
// Fused flash pass: per (b, ps, wave) process 16 rows of z ONCE:
//   s_p = scale * dot(z_p, qw); online softmax (m,l); acc += exp(s_p - m) z_p
// Each lane holds 12 floats (3 float4) of qw, z-row, and acc in registers.
// Writes per-wave partial (m, l, acc[768]) — no cross-wave sync needed.
// ---------------------------------------------------------------------------
__global__ __launch_bounds__(256) void fused_kernel(const float* __restrict__ z,
                                                    const float* __restrict__ qw,
                                                    float* __restrict__ macc,
                                                    float* __restrict__ ml) {
    const float scale = 0.03608439182435161f;  // 1/sqrt(768)
    int b    = blockIdx.x;
    int ps   = blockIdx.y;
    int tid  = threadIdx.x;
    int wave = tid >> 6;
    int lane = tid & 63;

    const float4* qw4 = (const float4*)qw;
    float4 q0 = qw4[lane], q1 = qw4[lane + 64], q2 = qw4[lane + 128];

    int p0 = ps * 64 + wave * 16;
    const float4* zr = (const float4*)(z + ((size_t)b * PP + p0) * DD);

    float m = -INFINITY, l = 0.f;
    float4 a0 = {0.f, 0.f, 0.f, 0.f}, a1 = a0, a2 = a0;

    for (int i = 0; i < 16; ++i) {
        float4 z0 = zr[lane], z1 = zr[lane + 64], z2 = zr[lane + 128];
        zr += DD / 4;   // next row

        float dacc = z0.x * q0.x + z0.y * q0.y + z0.z * q0.z + z0.w * q0.w
                   + z1.x * q1.x + z1.y * q1.y + z1.z * q1.z + z1.w * q1.w
                   + z2.x * q2.x + z2.y * q2.y + z2.z * q2.z + z2.w * q2.w;
#pragma unroll
        for (int off = 32; off >= 1; off >>= 1)
            dacc += __shfl_xor(dacc, off, 64);

        float s  = dacc * scale;
        float mn = fmaxf(m, s);
        float alpha = __expf(m - mn);   // first iter: exp(-inf)=0, zeroes nothing
        float e     = __expf(s - mn);
        l = l * alpha + e;
        a0.x = a0.x * alpha + e * z0.x;  a0.y = a0.y * alpha + e * z0.y;
        a0.z = a0.z * alpha + e * z0.z;  a0.w = a0.w * alpha + e * z0.w;
        a1.x = a1.x * alpha + e * z1.x;  a1.y = a1.y * alpha + e * z1.y;
        a1.z = a1.z * alpha + e * z1.z;  a1.w = a1.w * alpha + e * z1.w;
        a2.x = a2.x * alpha + e * z2.x;  a2.y = a2.y * alpha + e * z2.y;
        a2.z = a2.z * alpha + e * z2.z;  a2.w = a2.w * alpha + e * z2.w;
        m = mn;
    }

    int part = b * NPART + ps * 4 + wave;
    float4* ap4 = (float4*)(macc + (size_t)part * DD);
    ap4[lane] = a0; ap4[lane + 64] = a1; ap4[lane + 128] = a2;
    if (lane == 0) { ml[part * 2] = m; ml[part * 2 + 1] = l; }
}

// ---------------------------------------------------------------------------
// Combine 64 partials per batch:
//   M = max m_k;  L = sum exp(m_k-M) l_k;  out[d] = sum exp(m_k-M) acc_k[d] / L
// ---------------------------------------------------------------------------
__global__ __launch_bounds__(256) void reduce_kernel(const float* __restrict__ macc,
                                                     const float* __restrict__ ml,
                                                     float* __restrict__ out) {
    int b    = blockIdx.x;
    int tid  = threadIdx.x;
    int wave = tid >> 6;
    int lane = tid & 63;

    __shared__ float wts[NPART];
    __shared__ float Lsh;

    if (wave == 0) {
        float mk = ml[(b * NPART + lane) * 2];
        float lk = ml[(b * NPART + lane) * 2 + 1];
        float M = mk;
#pragma unroll
        for (int off = 32; off >= 1; off >>= 1) M = fmaxf(M, __shfl_xor(M, off, 64));
        float w = __expf(mk - M);
        float L = w * lk;
#pragma unroll
        for (int off = 32; off >= 1; off >>= 1) L += __shfl_xor(L, off, 64);
        wts[lane] = w;
        if (lane == 0) Lsh = L;
    }
    __syncthreads();

    float inv = 1.f / Lsh;
    const float* base = macc + (size_t)b * NPART * DD;
#pragma unroll
    for (int c = 0; c < 3; ++c) {
        int d = c * 256 + tid;
        float acc = 0.f;
#pragma unroll 8
        for (int k = 0; k < NPART; ++k) acc += wts[k] * base[(size_t)k * DD + d];
        out[b * DD + d] = acc * inv;
    }
}

// ---------------------------------------------------------------------------
extern "C" void kernel_launch(void* const* d_in, const int* in_sizes, int n_in,
                              void* d_out, int out_size, void* d_ws, size_t ws_size,
                              hipStream_t stream) {
    const float* z = (const float*)d_in[0];   // [B,P,D]
    const float* q = (const float*)d_in[1];   // [1,1,D]
    const float* W = (const float*)d_in[2];   // [D,D]
    float* out = (float*)d_out;               // [B,D]

    char* ws = (char*)d_ws;
    float* qw   = (float*)ws;                                  // 768 floats
    float* ml   = (float*)(ws + 4096);                         // 64*64*2 floats (32 KB)
    float* macc = (float*)(ws + 4096 + 65536);                 // 64*64*768 floats (12.6 MB)

    hipMemsetAsync(qw, 0, DD * sizeof(float), stream);
    dim3 qg(3, 32);
    qw_kernel<<<qg, 256, 0, stream>>>(q, W, qw);
    dim3 fg(BB, PS);
    fused_kernel<<<fg, 256, 0, stream>>>(z, qw, macc, ml);
    reduce_kernel<<<BB, 256, 0, stream>>>(macc, ml, out);
}

// Round 4
// 286.774 us; speedup vs baseline: 1.4048x; 1.0276x over previous
//
#include <hip/hip_runtime.h>
#include <math.h>

#define BB 64
#define PP 1024
#define DD 768
#define SS 8              // p-splits per batch: block covers 128 rows
#define TR 16             // rows per LDS tile
#define NT 8              // tiles per block = 128 / TR

// ---------------------------------------------------------------------------
// qw[d] = sum_e q[e] * W[e*D + d]  — grid (3, 32), atomicAdd combine
// ---------------------------------------------------------------------------
__global__ __launch_bounds__(256) void qw_kernel(const float* __restrict__ q,
                                                 const float* __restrict__ W,
                                                 float* __restrict__ qw) {
    int d  = blockIdx.x * 256 + threadIdx.x;
    int e0 = blockIdx.y * 24;
    float acc = 0.f;
#pragma unroll
    for (int i = 0; i < 24; ++i) {
        int e = e0 + i;
        acc += q[e] * W[(size_t)e * DD + d];
    }
    atomicAdd(&qw[d], acc);
}

// ---------------------------------------------------------------------------
// Fused single-pass attention pool, LDS-tiled.
// Block (b, split) processes 128 rows as 8 tiles of 16 rows:
//   stage 48KB tile -> barrier -> 16 dots (16 lanes/row, LDS) -> barrier ->
//   online-softmax rescale + accumulate (thread owns 3 d's) -> barrier.
// Writes one partial (m, l, acc[768]) per block.
// ---------------------------------------------------------------------------
__global__ __launch_bounds__(256) void fused_kernel(const float* __restrict__ z,
                                                    const float* __restrict__ qw,
                                                    float* __restrict__ macc,
                                                    float* __restrict__ ml) {
    const float scale = 0.03608439182435161f;   // 1/sqrt(768)
    __shared__ float zt[TR * DD];               // 48 KB tile
    __shared__ float qs[DD];                    // 3 KB
    __shared__ float sc[TR];                    // 16 row scores

    int b     = blockIdx.x;
    int split = blockIdx.y;
    int tid   = threadIdx.x;

    // load qw into LDS once
    for (int i = tid; i < DD; i += 256) qs[i] = qw[i];

    int row = tid >> 4;        // 0..15 : row within tile (for dot phase)
    int l16 = tid & 15;        // 0..15 : 16 lanes per row

    float m = -INFINITY, l = 0.f;
    float a0 = 0.f, a1 = 0.f, a2 = 0.f;         // d = tid, tid+256, tid+512

    const float4* gz = (const float4*)(z + ((size_t)b * PP + split * 128) * DD);
    float4*       lz = (float4*)zt;
    const float4* q4 = (const float4*)qs;

    __syncthreads();

    for (int t = 0; t < NT; ++t) {
        // ---- stage tile t: 48 KB = 3072 float4, 12 per thread, all loads
        //      issued back-to-back (12 KB in flight per wave) ----
        float4 tmp[12];
#pragma unroll
        for (int k = 0; k < 12; ++k) tmp[k] = gz[(size_t)t * 3072 + k * 256 + tid];
#pragma unroll
        for (int k = 0; k < 12; ++k) lz[k * 256 + tid] = tmp[k];
        __syncthreads();

        // ---- dot phase: 16 lanes per row, 12 float4 each ----
        float part = 0.f;
#pragma unroll
        for (int k = 0; k < 12; ++k) {
            float4 zv = lz[row * 192 + k * 16 + l16];
            float4 qv = q4[k * 16 + l16];
            part += zv.x * qv.x + zv.y * qv.y + zv.z * qv.z + zv.w * qv.w;
        }
#pragma unroll
        for (int mask = 8; mask >= 1; mask >>= 1)
            part += __shfl_xor(part, mask, 64);
        if (l16 == 0) sc[row] = part * scale;
        __syncthreads();

        // ---- online softmax update (all threads redundantly share m,l) ----
        float mt = sc[0];
#pragma unroll
        for (int r = 1; r < TR; ++r) mt = fmaxf(mt, sc[r]);
        float mn    = fmaxf(m, mt);
        float alpha = __expf(m - mn);            // first tile: exp(-inf)=0
        m = mn;
        l *= alpha;
        a0 *= alpha; a1 *= alpha; a2 *= alpha;
#pragma unroll
        for (int r = 0; r < TR; ++r) {
            float e = __expf(sc[r] - mn);
            l  += e;
            a0 += e * zt[r * DD + tid];
            a1 += e * zt[r * DD + tid + 256];
            a2 += e * zt[r * DD + tid + 512];
        }
        __syncthreads();   // protect zt before next stage
    }

    int part_idx = b * SS + split;
    float* ap = macc + (size_t)part_idx * DD;
    ap[tid] = a0; ap[tid + 256] = a1; ap[tid + 512] = a2;
    if (tid == 0) { ml[part_idx * 2] = m; ml[part_idx * 2 + 1] = l; }
}

// ---------------------------------------------------------------------------
// Combine 8 partials per batch:
//   M = max m_k; L = sum exp(m_k-M) l_k; out[d] = sum exp(m_k-M) acc_k[d] / L
// ---------------------------------------------------------------------------
__global__ __launch_bounds__(256) void reduce_kernel(const float* __restrict__ macc,
                                                     const float* __restrict__ ml,
                                                     float* __restrict__ out) {
    int b   = blockIdx.x;
    int tid = threadIdx.x;

    float mk[SS], lk[SS];
#pragma unroll
    for (int k = 0; k < SS; ++k) {
        mk[k] = ml[(b * SS + k) * 2];
        lk[k] = ml[(b * SS + k) * 2 + 1];
    }
    float M = mk[0];
#pragma unroll
    for (int k = 1; k < SS; ++k) M = fmaxf(M, mk[k]);
    float L = 0.f, w[SS];
#pragma unroll
    for (int k = 0; k < SS; ++k) { w[k] = __expf(mk[k] - M); L += w[k] * lk[k]; }
    float inv = 1.f / L;

    const float* base = macc + (size_t)b * SS * DD;
#pragma unroll
    for (int j = 0; j < 3; ++j) {
        int d = j * 256 + tid;
        float acc = 0.f;
#pragma unroll
        for (int k = 0; k < SS; ++k) acc += w[k] * base[(size_t)k * DD + d];
        out[b * DD + d] = acc * inv;
    }
}

// ---------------------------------------------------------------------------
extern "C" void kernel_launch(void* const* d_in, const int* in_sizes, int n_in,
                              void* d_out, int out_size, void* d_ws, size_t ws_size,
                              hipStream_t stream) {
    const float* z = (const float*)d_in[0];   // [B,P,D]
    const float* q = (const float*)d_in[1];   // [1,1,D]
    const float* W = (const float*)d_in[2];   // [D,D]
    float* out = (float*)d_out;               // [B,D]

    char* ws = (char*)d_ws;
    float* qw   = (float*)ws;                       // 768 floats
    float* ml   = (float*)(ws + 4096);              // 512*2 floats
    float* macc = (float*)(ws + 4096 + 8192);       // 512*768 floats (1.57 MB)

    hipMemsetAsync(qw, 0, DD * sizeof(float), stream);
    dim3 qg(3, 32);
    qw_kernel<<<qg, 256, 0, stream>>>(q, W, qw);
    dim3 fg(BB, SS);
    fused_kernel<<<fg, 256, 0, stream>>>(z, qw, macc, ml);
    reduce_kernel<<<BB, 256, 0, stream>>>(macc, ml, out);
}